// Round 1
// baseline (154.230 us; speedup 1.0000x reference)
//
#include <hip/hip_runtime.h>

// Perona-Malik anisotropic diffusion step, fp32, NCHW (64,1,1024,1024).
//   padded = reflect_pad(image, 1)
//   g      = conv3x3(padded, laplace)          (cross-correlation, VALID)
//   coeff  = exp(-g^2 / 0.01)
//   out    = clamp(image + g*coeff*0.15, 0, 1)
//
// Memory-bound: 256 MB in + 256 MB out -> ~81 us floor at 6.3 TB/s.
// Block = 256 threads = one full 1024-px row (4 px/thread, float4 aligned),
// iterated over a 16-row stripe so vertical halo rows are cache hits.

#define IMG_H 1024
#define IMG_W 1024
#define N_IMG 64
#define ROWS_PER_BLOCK 16

__device__ __forceinline__ void load_row6(const float* __restrict__ row,
                                          int x0, float v[6]) {
    // aligned 16B vector load for the 4 owned pixels
    const float4 m = *reinterpret_cast<const float4*>(row + x0);
    v[1] = m.x; v[2] = m.y; v[3] = m.z; v[4] = m.w;
    // column halos with reflection (pad=1, reflect: -1 -> 1, W -> W-2)
    int xl = x0 - 1;       if (xl < 0)      xl = 1;
    int xr = x0 + 4;       if (xr >= IMG_W) xr = IMG_W - 2;
    v[0] = row[xl];
    v[5] = row[xr];
}

__global__ __launch_bounds__(256)
void perona_malik_kernel(const float* __restrict__ img,
                         const float* __restrict__ lap,
                         float* __restrict__ out) {
    // 3x3 stencil coefficients (broadcast, cache-served)
    const float k00 = lap[0], k01 = lap[1], k02 = lap[2];
    const float k10 = lap[3], k11 = lap[4], k12 = lap[5];
    const float k20 = lap[6], k21 = lap[7], k22 = lap[8];

    const int   tid  = threadIdx.x;
    const int   x0   = tid * 4;                      // 4 px per thread
    const int   spi  = IMG_H / ROWS_PER_BLOCK;       // stripes per image
    const int   n    = blockIdx.x / spi;
    const int   strp = blockIdx.x % spi;

    const float* __restrict__ base  = img + (size_t)n * IMG_H * IMG_W;
    float*       __restrict__ obase = out + (size_t)n * IMG_H * IMG_W;

    const int y_begin = strp * ROWS_PER_BLOCK;
    const int y_end   = y_begin + ROWS_PER_BLOCK;

    for (int y = y_begin; y < y_end; ++y) {
        // reflected row indices (pad=1)
        int ym = y - 1; if (ym < 0)      ym = 1;
        int yp = y + 1; if (yp >= IMG_H) yp = IMG_H - 2;

        float a[6], b[6], c[6];
        load_row6(base + (size_t)ym * IMG_W, x0, a);
        load_row6(base + (size_t)y  * IMG_W, x0, b);
        load_row6(base + (size_t)yp * IMG_W, x0, c);

        float4 res;
        float* r = &res.x;
#pragma unroll
        for (int i = 0; i < 4; ++i) {
            float g = k00 * a[i]     + k01 * a[i + 1] + k02 * a[i + 2]
                    + k10 * b[i]     + k11 * b[i + 1] + k12 * b[i + 2]
                    + k20 * c[i]     + k21 * c[i + 1] + k22 * c[i + 2];
            // coeff = exp(-g^2 / DR^2), DR^2 = 0.01
            float coeff = __expf(-g * g * 100.0f);
            float v = b[i + 1] + g * coeff * 0.15f;
            r[i] = fminf(fmaxf(v, 0.0f), 1.0f);
        }
        *reinterpret_cast<float4*>(obase + (size_t)y * IMG_W + x0) = res;
    }
}

extern "C" void kernel_launch(void* const* d_in, const int* in_sizes, int n_in,
                              void* d_out, int out_size, void* d_ws, size_t ws_size,
                              hipStream_t stream) {
    const float* img = (const float*)d_in[0];
    const float* lap = (const float*)d_in[1];
    float*       out = (float*)d_out;

    const int blocks = N_IMG * (IMG_H / ROWS_PER_BLOCK);   // 4096
    perona_malik_kernel<<<blocks, 256, 0, stream>>>(img, lap, out);
}

// Round 3
// 88.868 us; speedup vs baseline: 1.7355x; 1.7355x over previous
//
#include <hip/hip_runtime.h>

// Perona-Malik diffusion step, fp32, NCHW (64,1,1024,1024).
// Rolling-register 3-row stencil, one global read per input row per block,
// software-pipelined prefetch of row y+2 while computing row y.
// Memory-bound target: 256 MB read + 256 MB write -> ~82 us at 6.3 TB/s.

#define IMG_H 1024
#define IMG_W 1024
#define N_IMG 64
#define ROWS_PER_BLOCK 32
#define STRIPES (IMG_H / ROWS_PER_BLOCK)   // 32

typedef float f32x4 __attribute__((ext_vector_type(4)));   // native vector: ok for nontemporal builtins

__device__ __forceinline__ void load_row6(const float* __restrict__ row,
                                          int x0, float v[6]) {
    // aligned 16B vector load for the 4 owned pixels
    const f32x4 m = *reinterpret_cast<const f32x4*>(row + x0);
    v[1] = m.x; v[2] = m.y; v[3] = m.z; v[4] = m.w;
    // column halos with reflection (pad=1): -1 -> 1, W -> W-2
    int xl = x0 - 1;       if (xl < 0)      xl = 1;
    int xr = x0 + 4;       if (xr >= IMG_W) xr = IMG_W - 2;
    v[0] = row[xl];
    v[5] = row[xr];
}

__global__ __launch_bounds__(256)
void perona_malik_kernel(const float* __restrict__ img,
                         const float* __restrict__ lap,
                         float* __restrict__ out) {
    const float k00 = lap[0], k01 = lap[1], k02 = lap[2];
    const float k10 = lap[3], k11 = lap[4], k12 = lap[5];
    const float k20 = lap[6], k21 = lap[7], k22 = lap[8];

    const int tid  = threadIdx.x;
    const int x0   = tid * 4;                 // 4 px per thread, float4-aligned
    const int n    = blockIdx.x / STRIPES;
    const int strp = blockIdx.x % STRIPES;

    const float* __restrict__ base  = img + (size_t)n * IMG_H * IMG_W;
    float*       __restrict__ obase = out + (size_t)n * IMG_H * IMG_W;

    const int y0   = strp * ROWS_PER_BLOCK;
    const int yend = y0 + ROWS_PER_BLOCK;

    // rolling rows: a = ry(y-1), b = y, c = ry(y+1); d = prefetch of ry(y+2)
    float a[6], b[6], c[6], d[6];
    {
        int ym = y0 - 1; if (ym < 0) ym = 1;           // reflect top edge
        load_row6(base + (size_t)ym * IMG_W, x0, a);
        load_row6(base + (size_t)y0 * IMG_W, x0, b);
        load_row6(base + (size_t)(y0 + 1) * IMG_W, x0, c);   // y0+1 <= 993 < H always
    }

    for (int y = y0; y < yend; ++y) {
        // prefetch the row needed as 'c' in the NEXT iteration (independent of
        // this iteration's compute -> latency hidden under compute+store)
        if (y + 1 < yend) {
            int t = y + 2; if (t >= IMG_H) t = IMG_H - 2;    // reflect bottom edge
            load_row6(base + (size_t)t * IMG_W, x0, d);
        }

        f32x4 res;
#pragma unroll
        for (int i = 0; i < 4; ++i) {
            float g = k00 * a[i] + k01 * a[i + 1] + k02 * a[i + 2]
                    + k10 * b[i] + k11 * b[i + 1] + k12 * b[i + 2]
                    + k20 * c[i] + k21 * c[i + 1] + k22 * c[i + 2];
            float coeff = __expf(-g * g * 100.0f);           // exp(-g^2/0.01)
            float v = b[i + 1] + g * coeff * 0.15f;
            res[i] = fminf(fmaxf(v, 0.0f), 1.0f);
        }
        // non-temporal: write stream must not evict the read stream from L2/L3
        __builtin_nontemporal_store(res,
            reinterpret_cast<f32x4*>(obase + (size_t)y * IMG_W + x0));

        // rotate rows (register renames / cheap v_movs)
#pragma unroll
        for (int i = 0; i < 6; ++i) { a[i] = b[i]; b[i] = c[i]; c[i] = d[i]; }
    }
}

extern "C" void kernel_launch(void* const* d_in, const int* in_sizes, int n_in,
                              void* d_out, int out_size, void* d_ws, size_t ws_size,
                              hipStream_t stream) {
    const float* img = (const float*)d_in[0];
    const float* lap = (const float*)d_in[1];
    float*       out = (float*)d_out;

    const int blocks = N_IMG * STRIPES;   // 2048 blocks = 32 waves/CU, one round
    perona_malik_kernel<<<blocks, 256, 0, stream>>>(img, lap, out);
}